// Round 1
// baseline (416.672 us; speedup 1.0000x reference)
//
#include <hip/hip_runtime.h>
#include <math.h>

#define N_CONS  100000
#define N_VARS  200000
#define N_EDGES 8000000
#define N_CAND  20000
#define C_FEAT  5
#define V_FEAT  19

// Pack variable[:,5] and constraint[:,2] into dense arrays (L2-resident),
// so the per-edge random gathers hit small contiguous buffers.
__global__ void pack_kernel(const float* __restrict__ variable,
                            const float* __restrict__ constraint,
                            float* __restrict__ var5,
                            float* __restrict__ cons2) {
    int i = blockIdx.x * blockDim.x + threadIdx.x;
    if (i < N_VARS) var5[i]  = variable[i * V_FEAT + 5];
    if (i < N_CONS) cons2[i] = constraint[i * C_FEAT + 2];
}

// msg[e] = var5[v_idx[e]] * edge_attr[e] + cons2[c_idx[e]];
// agg[v_idx[e]] += msg[e]  (atomic scatter-sum)
__global__ void edge_kernel(const int* __restrict__ c_idx,
                            const int* __restrict__ v_idx,
                            const float* __restrict__ edge_attr,
                            const float* __restrict__ var5,
                            const float* __restrict__ cons2,
                            float* __restrict__ agg) {
    int tid = blockIdx.x * blockDim.x + threadIdx.x;
    int stride = gridDim.x * blockDim.x;
    const int4*   c4 = (const int4*)c_idx;
    const int4*   v4 = (const int4*)v_idx;
    const float4* e4 = (const float4*)edge_attr;
    const int n4 = N_EDGES / 4;
    for (int i = tid; i < n4; i += stride) {
        int4   c  = c4[i];
        int4   v  = v4[i];
        float4 ea = e4[i];
        float m0 = var5[v.x] * ea.x + cons2[c.x];
        float m1 = var5[v.y] * ea.y + cons2[c.y];
        float m2 = var5[v.z] * ea.z + cons2[c.z];
        float m3 = var5[v.w] * ea.w + cons2[c.w];
        atomicAdd(agg + v.x, m0);
        atomicAdd(agg + v.y, m1);
        atomicAdd(agg + v.z, m2);
        atomicAdd(agg + v.w, m3);
    }
}

// out[i] = agg[v] * variable[v,0] + sqrt(abs(variable[v,3])), v = cand[i]
__global__ void out_kernel(const int* __restrict__ cand,
                           const float* __restrict__ agg,
                           const float* __restrict__ variable,
                           float* __restrict__ out) {
    int i = blockIdx.x * blockDim.x + threadIdx.x;
    if (i < N_CAND) {
        int v = cand[i];
        out[i] = agg[v] * variable[v * V_FEAT + 0] + sqrtf(fabsf(variable[v * V_FEAT + 3]));
    }
}

extern "C" void kernel_launch(void* const* d_in, const int* in_sizes, int n_in,
                              void* d_out, int out_size, void* d_ws, size_t ws_size,
                              hipStream_t stream) {
    const float* constraint = (const float*)d_in[0];   // [N_CONS, 5]
    const float* variable   = (const float*)d_in[1];   // [N_VARS, 19]
    const int*   cv_edge    = (const int*)d_in[2];     // [2, N_EDGES]
    const float* edge_attr  = (const float*)d_in[3];   // [N_EDGES]
    const int*   cand_mask  = (const int*)d_in[4];     // [N_CAND]
    float* out = (float*)d_out;

    const int* c_idx = cv_edge;            // row 0
    const int* v_idx = cv_edge + N_EDGES;  // row 1

    // Workspace layout: agg[N_VARS] | var5[N_VARS] | cons2[N_CONS]
    float* agg   = (float*)d_ws;
    float* var5  = agg + N_VARS;
    float* cons2 = var5 + N_VARS;

    // Zero the accumulator every call (harness does not re-poison between replays).
    hipMemsetAsync(agg, 0, N_VARS * sizeof(float), stream);

    {
        int threads = 256;
        int blocks = (N_VARS + threads - 1) / threads;
        pack_kernel<<<blocks, threads, 0, stream>>>(variable, constraint, var5, cons2);
    }
    {
        int threads = 256;
        int blocks = 2048;  // grid-stride over N_EDGES/4 work items
        edge_kernel<<<blocks, threads, 0, stream>>>(c_idx, v_idx, edge_attr,
                                                    var5, cons2, agg);
    }
    {
        int threads = 256;
        int blocks = (N_CAND + threads - 1) / threads;
        out_kernel<<<blocks, threads, 0, stream>>>(cand_mask, agg, variable, out);
    }
}

// Round 2
// 75.240 us; speedup vs baseline: 5.5379x; 5.5379x over previous
//
#include <hip/hip_runtime.h>
#include <math.h>

#define N_CONS  100000
#define N_VARS  200000
#define N_EDGES 8000000
#define N_CAND  20000
#define C_FEAT  5
#define V_FEAT  19
#define BITMAP_WORDS ((N_VARS + 31) / 32)

// Pack variable[:,5] and constraint[:,2] into dense arrays (L2-resident),
// and build the candidate bitmap (which variables ever appear in cand_mask).
__global__ void pack_kernel(const float* __restrict__ variable,
                            const float* __restrict__ constraint,
                            const int* __restrict__ cand,
                            float* __restrict__ var5,
                            float* __restrict__ cons2,
                            unsigned int* __restrict__ bitmap) {
    int i = blockIdx.x * blockDim.x + threadIdx.x;
    if (i < N_VARS) var5[i]  = variable[i * V_FEAT + 5];
    if (i < N_CONS) cons2[i] = constraint[i * C_FEAT + 2];
    if (i < N_CAND) {
        int v = cand[i];
        atomicOr(&bitmap[v >> 5], 1u << (v & 31));
    }
}

// For each edge: if target variable is a candidate, scatter-add its message.
// Non-candidate targets are never read by the output -> skip (10.5x fewer
// device atomics; atomics are the bottleneck, 32B HBM write-through each).
__global__ void edge_kernel(const int* __restrict__ c_idx,
                            const int* __restrict__ v_idx,
                            const float* __restrict__ edge_attr,
                            const float* __restrict__ var5,
                            const float* __restrict__ cons2,
                            const unsigned int* __restrict__ bitmap,
                            float* __restrict__ agg) {
    int tid = blockIdx.x * blockDim.x + threadIdx.x;
    int stride = gridDim.x * blockDim.x;
    const int4*   c4 = (const int4*)c_idx;
    const int4*   v4 = (const int4*)v_idx;
    const float4* e4 = (const float4*)edge_attr;
    const int n4 = N_EDGES / 4;
    for (int i = tid; i < n4; i += stride) {
        int4   c  = c4[i];
        int4   v  = v4[i];
        float4 ea = e4[i];
        if ((bitmap[v.x >> 5] >> (v.x & 31)) & 1u)
            atomicAdd(agg + v.x, var5[v.x] * ea.x + cons2[c.x]);
        if ((bitmap[v.y >> 5] >> (v.y & 31)) & 1u)
            atomicAdd(agg + v.y, var5[v.y] * ea.y + cons2[c.y]);
        if ((bitmap[v.z >> 5] >> (v.z & 31)) & 1u)
            atomicAdd(agg + v.z, var5[v.z] * ea.z + cons2[c.z]);
        if ((bitmap[v.w >> 5] >> (v.w & 31)) & 1u)
            atomicAdd(agg + v.w, var5[v.w] * ea.w + cons2[c.w]);
    }
}

// out[i] = agg[v] * variable[v,0] + sqrt(abs(variable[v,3])), v = cand[i]
__global__ void out_kernel(const int* __restrict__ cand,
                           const float* __restrict__ agg,
                           const float* __restrict__ variable,
                           float* __restrict__ out) {
    int i = blockIdx.x * blockDim.x + threadIdx.x;
    if (i < N_CAND) {
        int v = cand[i];
        out[i] = agg[v] * variable[v * V_FEAT + 0] + sqrtf(fabsf(variable[v * V_FEAT + 3]));
    }
}

extern "C" void kernel_launch(void* const* d_in, const int* in_sizes, int n_in,
                              void* d_out, int out_size, void* d_ws, size_t ws_size,
                              hipStream_t stream) {
    const float* constraint = (const float*)d_in[0];   // [N_CONS, 5]
    const float* variable   = (const float*)d_in[1];   // [N_VARS, 19]
    const int*   cv_edge    = (const int*)d_in[2];     // [2, N_EDGES]
    const float* edge_attr  = (const float*)d_in[3];   // [N_EDGES]
    const int*   cand_mask  = (const int*)d_in[4];     // [N_CAND]
    float* out = (float*)d_out;

    const int* c_idx = cv_edge;            // row 0
    const int* v_idx = cv_edge + N_EDGES;  // row 1

    // Workspace layout: agg[N_VARS] | var5[N_VARS] | cons2[N_CONS] | bitmap
    float* agg   = (float*)d_ws;
    float* var5  = agg + N_VARS;
    float* cons2 = var5 + N_VARS;
    unsigned int* bitmap = (unsigned int*)(cons2 + N_CONS);

    // Zero accumulator + bitmap every call (deterministic; harness doesn't
    // re-poison between replays).
    hipMemsetAsync(agg, 0, N_VARS * sizeof(float), stream);
    hipMemsetAsync(bitmap, 0, BITMAP_WORDS * sizeof(unsigned int), stream);

    {
        int threads = 256;
        int blocks = (N_VARS + threads - 1) / threads;
        pack_kernel<<<blocks, threads, 0, stream>>>(variable, constraint, cand_mask,
                                                    var5, cons2, bitmap);
    }
    {
        int threads = 256;
        int blocks = 2048;  // grid-stride over N_EDGES/4 work items
        edge_kernel<<<blocks, threads, 0, stream>>>(c_idx, v_idx, edge_attr,
                                                    var5, cons2, bitmap, agg);
    }
    {
        int threads = 256;
        int blocks = (N_CAND + threads - 1) / threads;
        out_kernel<<<blocks, threads, 0, stream>>>(cand_mask, agg, variable, out);
    }
}

// Round 3
// 71.317 us; speedup vs baseline: 5.8426x; 1.0550x over previous
//
#include <hip/hip_runtime.h>
#include <math.h>

#define N_CONS  100000
#define N_VARS  200000
#define N_EDGES 8000000
#define N_CAND  20000
#define C_FEAT  5
#define V_FEAT  19
#define BITMAP_WORDS ((N_VARS + 31) / 32)

// Pack variable[:,5] and constraint[:,2] into dense arrays (L2-resident),
// and build the candidate bitmap (which variables ever appear in cand_mask).
__global__ void pack_kernel(const float* __restrict__ variable,
                            const float* __restrict__ constraint,
                            const int* __restrict__ cand,
                            float* __restrict__ var5,
                            float* __restrict__ cons2,
                            unsigned int* __restrict__ bitmap) {
    int i = blockIdx.x * blockDim.x + threadIdx.x;
    if (i < N_VARS) var5[i]  = variable[i * V_FEAT + 5];
    if (i < N_CONS) cons2[i] = constraint[i * C_FEAT + 2];
    if (i < N_CAND) {
        int v = cand[i];
        atomicOr(&bitmap[v >> 5], 1u << (v & 31));
    }
}

// One int4-group of 4 edges per thread, no loop. All loads (stream + bitmap
// + gathers) are issued branchlessly so they overlap in one vmcnt window;
// only the atomicAdd (fire-and-forget, no wait) is predicated. Dead lanes
// gather address 0 -> same-line broadcast, L1-hot, free.
__global__ void edge_kernel(const int* __restrict__ c_idx,
                            const int* __restrict__ v_idx,
                            const float* __restrict__ edge_attr,
                            const float* __restrict__ var5,
                            const float* __restrict__ cons2,
                            const unsigned int* __restrict__ bitmap,
                            float* __restrict__ agg) {
    int i = blockIdx.x * blockDim.x + threadIdx.x;
    const int n4 = N_EDGES / 4;
    if (i >= n4) return;

    int4   v  = ((const int4*)v_idx)[i];
    int4   c  = ((const int4*)c_idx)[i];
    float4 ea = ((const float4*)edge_attr)[i];

    bool k0 = (bitmap[v.x >> 5] >> (v.x & 31)) & 1u;
    bool k1 = (bitmap[v.y >> 5] >> (v.y & 31)) & 1u;
    bool k2 = (bitmap[v.z >> 5] >> (v.z & 31)) & 1u;
    bool k3 = (bitmap[v.w >> 5] >> (v.w & 31)) & 1u;

    // Branchless gather addresses (0 = harmless dummy for dead lanes).
    int va0 = k0 ? v.x : 0,  ca0 = k0 ? c.x : 0;
    int va1 = k1 ? v.y : 0,  ca1 = k1 ? c.y : 0;
    int va2 = k2 ? v.z : 0,  ca2 = k2 ? c.z : 0;
    int va3 = k3 ? v.w : 0,  ca3 = k3 ? c.w : 0;

    float m0 = var5[va0] * ea.x + cons2[ca0];
    float m1 = var5[va1] * ea.y + cons2[ca1];
    float m2 = var5[va2] * ea.z + cons2[ca2];
    float m3 = var5[va3] * ea.w + cons2[ca3];

    if (k0) atomicAdd(agg + v.x, m0);
    if (k1) atomicAdd(agg + v.y, m1);
    if (k2) atomicAdd(agg + v.z, m2);
    if (k3) atomicAdd(agg + v.w, m3);
}

// out[i] = agg[v] * variable[v,0] + sqrt(abs(variable[v,3])), v = cand[i]
__global__ void out_kernel(const int* __restrict__ cand,
                           const float* __restrict__ agg,
                           const float* __restrict__ variable,
                           float* __restrict__ out) {
    int i = blockIdx.x * blockDim.x + threadIdx.x;
    if (i < N_CAND) {
        int v = cand[i];
        out[i] = agg[v] * variable[v * V_FEAT + 0] + sqrtf(fabsf(variable[v * V_FEAT + 3]));
    }
}

extern "C" void kernel_launch(void* const* d_in, const int* in_sizes, int n_in,
                              void* d_out, int out_size, void* d_ws, size_t ws_size,
                              hipStream_t stream) {
    const float* constraint = (const float*)d_in[0];   // [N_CONS, 5]
    const float* variable   = (const float*)d_in[1];   // [N_VARS, 19]
    const int*   cv_edge    = (const int*)d_in[2];     // [2, N_EDGES]
    const float* edge_attr  = (const float*)d_in[3];   // [N_EDGES]
    const int*   cand_mask  = (const int*)d_in[4];     // [N_CAND]
    float* out = (float*)d_out;

    const int* c_idx = cv_edge;            // row 0
    const int* v_idx = cv_edge + N_EDGES;  // row 1

    // Workspace layout: agg[N_VARS] | var5[N_VARS] | cons2[N_CONS] | bitmap
    float* agg   = (float*)d_ws;
    float* var5  = agg + N_VARS;
    float* cons2 = var5 + N_VARS;
    unsigned int* bitmap = (unsigned int*)(cons2 + N_CONS);

    // Zero accumulator + bitmap every call (deterministic; harness doesn't
    // re-poison between replays).
    hipMemsetAsync(agg, 0, N_VARS * sizeof(float), stream);
    hipMemsetAsync(bitmap, 0, BITMAP_WORDS * sizeof(unsigned int), stream);

    {
        int threads = 256;
        int blocks = (N_VARS + threads - 1) / threads;
        pack_kernel<<<blocks, threads, 0, stream>>>(variable, constraint, cand_mask,
                                                    var5, cons2, bitmap);
    }
    {
        int threads = 256;
        const int n4 = N_EDGES / 4;
        int blocks = (n4 + threads - 1) / threads;  // 8192: one int4-group/thread
        edge_kernel<<<blocks, threads, 0, stream>>>(c_idx, v_idx, edge_attr,
                                                    var5, cons2, bitmap, agg);
    }
    {
        int threads = 256;
        int blocks = (N_CAND + threads - 1) / threads;
        out_kernel<<<blocks, threads, 0, stream>>>(cand_mask, agg, variable, out);
    }
}

// Round 4
// 71.056 us; speedup vs baseline: 5.8640x; 1.0037x over previous
//
#include <hip/hip_runtime.h>
#include <math.h>

#define N_CONS  100000
#define N_VARS  200000
#define N_EDGES 8000000
#define N_CAND  20000
#define C_FEAT  5
#define V_FEAT  19
#define BITMAP_WORDS ((N_VARS + 31) / 32)   // 6250 -> pad to 6400 for uint4 copy
#define BITMAP_WORDS_PAD 6400

// Pack variable[:,5] and constraint[:,2] into dense arrays (L2-resident),
// and build the candidate bitmap (which variables ever appear in cand_mask).
__global__ void pack_kernel(const float* __restrict__ variable,
                            const float* __restrict__ constraint,
                            const int* __restrict__ cand,
                            float* __restrict__ var5,
                            float* __restrict__ cons2,
                            unsigned int* __restrict__ bitmap) {
    int i = blockIdx.x * blockDim.x + threadIdx.x;
    if (i < N_VARS) var5[i]  = variable[i * V_FEAT + 5];
    if (i < N_CONS) cons2[i] = constraint[i * C_FEAT + 2];
    if (i < N_CAND) {
        int v = cand[i];
        atomicOr(&bitmap[v >> 5], 1u << (v & 31));
    }
}

// Edge phase. The candidate bitmap lives in LDS: a divergent ds_read_b32 is
// ~9 cyc/wave (random 32-bank aliasing) vs ~90 cyc/wave for the same access
// as a divergent global load (TA processes one unique line/cycle). Gathers
// for dead lanes are pinned to address 0 (line-broadcast, free); atomics are
// predicated fire-and-forget.
__global__ void __launch_bounds__(256)
edge_kernel(const int* __restrict__ c_idx,
            const int* __restrict__ v_idx,
            const float* __restrict__ edge_attr,
            const float* __restrict__ var5,
            const float* __restrict__ cons2,
            const unsigned int* __restrict__ bitmap,
            float* __restrict__ agg) {
    __shared__ unsigned int lds_bm[BITMAP_WORDS_PAD];

    // Cooperative coalesced copy of the 25.6 KB bitmap into LDS.
    {
        const uint4* src = (const uint4*)bitmap;
        uint4* dst = (uint4*)lds_bm;
        for (int j = threadIdx.x; j < BITMAP_WORDS_PAD / 4; j += blockDim.x)
            dst[j] = src[j];
    }
    __syncthreads();

    const int n4 = N_EDGES / 4;
    int stride = gridDim.x * blockDim.x;
    for (int i = blockIdx.x * blockDim.x + threadIdx.x; i < n4; i += stride) {
        int4   v  = ((const int4*)v_idx)[i];
        int4   c  = ((const int4*)c_idx)[i];
        float4 ea = ((const float4*)edge_attr)[i];

        bool k0 = (lds_bm[v.x >> 5] >> (v.x & 31)) & 1u;
        bool k1 = (lds_bm[v.y >> 5] >> (v.y & 31)) & 1u;
        bool k2 = (lds_bm[v.z >> 5] >> (v.z & 31)) & 1u;
        bool k3 = (lds_bm[v.w >> 5] >> (v.w & 31)) & 1u;

        // Branchless gather addresses (0 = harmless dummy for dead lanes).
        int va0 = k0 ? v.x : 0,  ca0 = k0 ? c.x : 0;
        int va1 = k1 ? v.y : 0,  ca1 = k1 ? c.y : 0;
        int va2 = k2 ? v.z : 0,  ca2 = k2 ? c.z : 0;
        int va3 = k3 ? v.w : 0,  ca3 = k3 ? c.w : 0;

        float m0 = var5[va0] * ea.x + cons2[ca0];
        float m1 = var5[va1] * ea.y + cons2[ca1];
        float m2 = var5[va2] * ea.z + cons2[ca2];
        float m3 = var5[va3] * ea.w + cons2[ca3];

        if (k0) atomicAdd(agg + v.x, m0);
        if (k1) atomicAdd(agg + v.y, m1);
        if (k2) atomicAdd(agg + v.z, m2);
        if (k3) atomicAdd(agg + v.w, m3);
    }
}

// out[i] = agg[v] * variable[v,0] + sqrt(abs(variable[v,3])), v = cand[i]
__global__ void out_kernel(const int* __restrict__ cand,
                           const float* __restrict__ agg,
                           const float* __restrict__ variable,
                           float* __restrict__ out) {
    int i = blockIdx.x * blockDim.x + threadIdx.x;
    if (i < N_CAND) {
        int v = cand[i];
        out[i] = agg[v] * variable[v * V_FEAT + 0] + sqrtf(fabsf(variable[v * V_FEAT + 3]));
    }
}

extern "C" void kernel_launch(void* const* d_in, const int* in_sizes, int n_in,
                              void* d_out, int out_size, void* d_ws, size_t ws_size,
                              hipStream_t stream) {
    const float* constraint = (const float*)d_in[0];   // [N_CONS, 5]
    const float* variable   = (const float*)d_in[1];   // [N_VARS, 19]
    const int*   cv_edge    = (const int*)d_in[2];     // [2, N_EDGES]
    const float* edge_attr  = (const float*)d_in[3];   // [N_EDGES]
    const int*   cand_mask  = (const int*)d_in[4];     // [N_CAND]
    float* out = (float*)d_out;

    const int* c_idx = cv_edge;            // row 0
    const int* v_idx = cv_edge + N_EDGES;  // row 1

    // Workspace layout: agg[N_VARS] | var5[N_VARS] | cons2[N_CONS] | bitmap(pad)
    float* agg   = (float*)d_ws;
    float* var5  = agg + N_VARS;
    float* cons2 = var5 + N_VARS;
    unsigned int* bitmap = (unsigned int*)(cons2 + N_CONS);

    // Zero accumulator + bitmap (incl. pad) every call (deterministic;
    // harness doesn't re-poison between replays).
    hipMemsetAsync(agg, 0, N_VARS * sizeof(float), stream);
    hipMemsetAsync(bitmap, 0, BITMAP_WORDS_PAD * sizeof(unsigned int), stream);

    {
        int threads = 256;
        int blocks = (N_VARS + threads - 1) / threads;
        pack_kernel<<<blocks, threads, 0, stream>>>(variable, constraint, cand_mask,
                                                    var5, cons2, bitmap);
    }
    {
        int threads = 256;
        int blocks = 2048;  // grid-stride: 4 int4-groups/thread; 25.6KB LDS -> 6 blocks/CU
        edge_kernel<<<blocks, threads, 0, stream>>>(c_idx, v_idx, edge_attr,
                                                    var5, cons2, bitmap, agg);
    }
    {
        int threads = 256;
        int blocks = (N_CAND + threads - 1) / threads;
        out_kernel<<<blocks, threads, 0, stream>>>(cand_mask, agg, variable, out);
    }
}

// Round 5
// 56.851 us; speedup vs baseline: 7.3292x; 1.2499x over previous
//
#include <hip/hip_runtime.h>
#include <math.h>

#define N_CONS  100000
#define N_VARS  200000
#define N_EDGES 8000000
#define N_CAND  20000
#define C_FEAT  5
#define V_FEAT  19
#define BM_WORDS      6250
#define BM_WORDS_PAD  6400          // pad for uint4 copies
#define ACC_SLOTS     20000         // max distinct candidates = N_CAND
#define EDGE_BLOCKS   256           // 1 per CU
#define KSLICES       8
#define KS_LEN        (EDGE_BLOCKS / KSLICES)   // 32
#define CID_BLOCKS    ((ACC_SLOTS + 255) / 256) // 79

// Pack variable[:,5], constraint[:,2] into dense L2-resident arrays and
// build the candidate bitmap.
__global__ void pack_kernel(const float* __restrict__ variable,
                            const float* __restrict__ constraint,
                            const int* __restrict__ cand,
                            float* __restrict__ var5,
                            float* __restrict__ cons2,
                            unsigned int* __restrict__ bitmap) {
    int i = blockIdx.x * blockDim.x + threadIdx.x;
    if (i < N_VARS) var5[i]  = variable[i * V_FEAT + 5];
    if (i < N_CONS) cons2[i] = constraint[i * C_FEAT + 2];
    if (i < N_CAND) {
        int v = cand[i];
        atomicOr(&bitmap[v >> 5], 1u << (v & 31));
    }
}

// Exclusive popcount-prefix over bitmap words -> u16 (max ~20000 < 65536).
// One block of 1024 threads, 7 words each (7168 >= 6400).
__global__ void __launch_bounds__(1024)
scan_kernel(const unsigned int* __restrict__ bitmap,
            unsigned short* __restrict__ prefix) {
    __shared__ unsigned int s[1024];
    const int CH = 7;
    int t = threadIdx.x;
    int base = t * CH;
    unsigned int loc[CH];
    unsigned int sum = 0;
#pragma unroll
    for (int j = 0; j < CH; ++j) {
        int w = base + j;
        loc[j] = sum;                                   // local exclusive
        sum += (w < BM_WORDS_PAD) ? __popc(bitmap[w]) : 0u;
    }
    s[t] = sum;
    __syncthreads();
    for (int off = 1; off < 1024; off <<= 1) {          // Hillis-Steele inclusive
        unsigned int v = (t >= off) ? s[t - off] : 0u;
        __syncthreads();
        s[t] += v;
        __syncthreads();
    }
    unsigned int ebase = s[t] - sum;                    // exclusive base
#pragma unroll
    for (int j = 0; j < CH; ++j) {
        int w = base + j;
        if (w < BM_WORDS_PAD) prefix[w] = (unsigned short)(ebase + loc[j]);
    }
}

// Edge phase: bitmap + prefix + compact accumulator all in LDS (118 KB).
// Kept edges ds-atomicAdd into the compact accumulator; ZERO global atomics.
// Flush is a coalesced 80 KB store per block into partials[block][cid].
__global__ void __launch_bounds__(1024)
edge_kernel(const int* __restrict__ c_idx,
            const int* __restrict__ v_idx,
            const float* __restrict__ edge_attr,
            const float* __restrict__ var5,
            const float* __restrict__ cons2,
            const unsigned int* __restrict__ bitmap,
            const unsigned short* __restrict__ prefix,
            float* __restrict__ partials) {
    __shared__ unsigned int   lds_bm[BM_WORDS_PAD];
    __shared__ unsigned short lds_pf[BM_WORDS_PAD];
    __shared__ float          lds_acc[ACC_SLOTS];

    // Coalesced LDS fills.
    {
        const uint4* src = (const uint4*)bitmap;
        uint4* dst = (uint4*)lds_bm;
        for (int j = threadIdx.x; j < BM_WORDS_PAD / 4; j += blockDim.x)
            dst[j] = src[j];
        const uint4* ps = (const uint4*)prefix;
        uint4* pd = (uint4*)lds_pf;
        for (int j = threadIdx.x; j < BM_WORDS_PAD / 8; j += blockDim.x)
            pd[j] = ps[j];
        for (int j = threadIdx.x; j < ACC_SLOTS; j += blockDim.x)
            lds_acc[j] = 0.0f;
    }
    __syncthreads();

    const int nch = N_EDGES / 8;            // 8 edges per chunk
    int stride = gridDim.x * blockDim.x;
    const int4*   v4 = (const int4*)v_idx;
    const int4*   c4 = (const int4*)c_idx;
    const float4* e4 = (const float4*)edge_attr;

    for (int g = blockIdx.x * blockDim.x + threadIdx.x; g < nch; g += stride) {
        int4   va = v4[2 * g],     vb = v4[2 * g + 1];
        int4   ca = c4[2 * g],     cb = c4[2 * g + 1];
        float4 ea = e4[2 * g],     eb = e4[2 * g + 1];

#define PROC(vv, cc, ee)                                                     \
        {                                                                    \
            unsigned int word = lds_bm[(vv) >> 5];                           \
            bool keep = (word >> ((vv) & 31)) & 1u;                          \
            int gv = keep ? (vv) : 0, gc = keep ? (cc) : 0;                  \
            float m = var5[gv] * (ee) + cons2[gc];                           \
            if (keep) {                                                      \
                int cid = (int)lds_pf[(vv) >> 5] +                           \
                          __popc(word & ((1u << ((vv) & 31)) - 1u));         \
                atomicAdd(&lds_acc[cid], m);                                 \
            }                                                                \
        }
        PROC(va.x, ca.x, ea.x)  PROC(va.y, ca.y, ea.y)
        PROC(va.z, ca.z, ea.z)  PROC(va.w, ca.w, ea.w)
        PROC(vb.x, cb.x, eb.x)  PROC(vb.y, cb.y, eb.y)
        PROC(vb.z, cb.z, eb.z)  PROC(vb.w, cb.w, eb.w)
#undef PROC
    }
    __syncthreads();

    // Coalesced flush: partials[block][0..ACC_SLOTS)
    {
        float4* dst = (float4*)(partials + (size_t)blockIdx.x * ACC_SLOTS);
        const float4* src = (const float4*)lds_acc;
        for (int j = threadIdx.x; j < ACC_SLOTS / 4; j += blockDim.x)
            dst[j] = src[j];
    }
}

// Stage-1 reduce: p2[ks][cid] = sum over k in slice ks of partials[k][cid].
// Coalesced: consecutive threads read consecutive cids.
__global__ void reduce1_kernel(const float* __restrict__ partials,
                               float* __restrict__ p2) {
    int cb = blockIdx.x % CID_BLOCKS;
    int ks = blockIdx.x / CID_BLOCKS;
    int cid = cb * 256 + threadIdx.x;
    if (cid >= ACC_SLOTS) return;
    float acc = 0.0f;
#pragma unroll
    for (int k = 0; k < KS_LEN; ++k)
        acc += partials[(size_t)(ks * KS_LEN + k) * ACC_SLOTS + cid];
    p2[(size_t)ks * ACC_SLOTS + cid] = acc;
}

// out[i] = agg * variable[v,0] + sqrt(abs(variable[v,3])), v = cand[i],
// agg = sum of the 8 k-slice partials for v's compact id.
__global__ void out_kernel(const int* __restrict__ cand,
                           const float* __restrict__ p2,
                           const unsigned int* __restrict__ bitmap,
                           const unsigned short* __restrict__ prefix,
                           const float* __restrict__ variable,
                           float* __restrict__ out) {
    int i = blockIdx.x * blockDim.x + threadIdx.x;
    if (i >= N_CAND) return;
    int v = cand[i];
    unsigned int word = bitmap[v >> 5];
    int cid = (int)prefix[v >> 5] + __popc(word & ((1u << (v & 31)) - 1u));
    float acc = 0.0f;
#pragma unroll
    for (int s = 0; s < KSLICES; ++s)
        acc += p2[(size_t)s * ACC_SLOTS + cid];
    out[i] = acc * variable[v * V_FEAT + 0] + sqrtf(fabsf(variable[v * V_FEAT + 3]));
}

extern "C" void kernel_launch(void* const* d_in, const int* in_sizes, int n_in,
                              void* d_out, int out_size, void* d_ws, size_t ws_size,
                              hipStream_t stream) {
    const float* constraint = (const float*)d_in[0];   // [N_CONS, 5]
    const float* variable   = (const float*)d_in[1];   // [N_VARS, 19]
    const int*   cv_edge    = (const int*)d_in[2];     // [2, N_EDGES]
    const float* edge_attr  = (const float*)d_in[3];   // [N_EDGES]
    const int*   cand_mask  = (const int*)d_in[4];     // [N_CAND]
    float* out = (float*)d_out;

    const int* c_idx = cv_edge;            // row 0
    const int* v_idx = cv_edge + N_EDGES;  // row 1

    // ws layout (all 16B-aligned):
    // var5[200000] f | cons2[100000] f | bitmap[6400] u32 | prefix[6400] u16 |
    // partials[256*20000] f | p2[8*20000] f     -> ~22.4 MB total
    float* var5  = (float*)d_ws;
    float* cons2 = var5 + N_VARS;
    unsigned int*   bitmap = (unsigned int*)(cons2 + N_CONS);
    unsigned short* prefix = (unsigned short*)(bitmap + BM_WORDS_PAD);
    float* partials = (float*)(prefix + BM_WORDS_PAD);
    float* p2       = partials + (size_t)EDGE_BLOCKS * ACC_SLOTS;

    // Only the bitmap needs zeroing (everything else fully overwritten).
    hipMemsetAsync(bitmap, 0, BM_WORDS_PAD * sizeof(unsigned int), stream);

    {
        int threads = 256;
        int blocks = (N_VARS + threads - 1) / threads;
        pack_kernel<<<blocks, threads, 0, stream>>>(variable, constraint, cand_mask,
                                                    var5, cons2, bitmap);
    }
    scan_kernel<<<1, 1024, 0, stream>>>(bitmap, prefix);
    edge_kernel<<<EDGE_BLOCKS, 1024, 0, stream>>>(c_idx, v_idx, edge_attr,
                                                  var5, cons2, bitmap, prefix,
                                                  partials);
    reduce1_kernel<<<CID_BLOCKS * KSLICES, 256, 0, stream>>>(partials, p2);
    {
        int threads = 256;
        int blocks = (N_CAND + threads - 1) / threads;
        out_kernel<<<blocks, threads, 0, stream>>>(cand_mask, p2, bitmap, prefix,
                                                   variable, out);
    }
}